// Round 10
// baseline (113.700 us; speedup 1.0000x reference)
//
#include <hip/hip_runtime.h>
#include <math.h>
#include <stdint.h>

typedef __bf16 bf16;
typedef __bf16 bf16x8 __attribute__((ext_vector_type(8)));
typedef __bf16 bf16x4 __attribute__((ext_vector_type(4)));
typedef float f32x4 __attribute__((ext_vector_type(4)));
typedef float f32x16 __attribute__((ext_vector_type(16)));
typedef unsigned int u32;

// element index into a [rows][64] bf16 tile, XOR-swizzled in 16B (8-elem) chunks
__device__ __forceinline__ int swz(int row, int chunk) {
    return row * 64 + ((chunk ^ (row & 7)) << 3);
}

// async 16B global->LDS; lds must be wave-uniform base (HW adds lane*16)
__device__ __forceinline__ void gld16(void* lds, const void* g) {
    __builtin_amdgcn_global_load_lds(
        (const __attribute__((address_space(1))) u32*)g,
        (__attribute__((address_space(3))) u32*)lds, 16, 0, 0);
}

// 4-wave staging of a 64x64 bf16 tile: each wave issues TWO gld16 (16 rows).
// Linear LDS dest + inverse-XOR on the SOURCE chunk so swizzled reads see
// LDS[row][chunk^(row&7)] == src[row][chunk].
__device__ __forceinline__ void stage16(bf16* dst, const bf16* src, size_t srcStride,
                                        int w, int l) {
    #pragma unroll
    for (int i = 0; i < 2; ++i) {
        const int br = w * 16 + i * 8;
        const int r = br + (l >> 3);
        const int gs = (l & 7) ^ (r & 7);
        gld16(dst + br * 64, src + (size_t)r * srcStride + gs * 8);
    }
}

__global__ void cast_bf16_k(const float* __restrict__ src, bf16* __restrict__ dst, int n) {
    const int stride = gridDim.x * blockDim.x * 4;
    for (int i = (blockIdx.x * blockDim.x + threadIdx.x) * 4; i < n; i += stride) {
        float4 v = *(const float4*)(src + i);
        bf16x4 o = {(bf16)v.x, (bf16)v.y, (bf16)v.z, (bf16)v.w};
        *(bf16x4*)(dst + i) = o;
    }
}

__global__ void cast3_bf16_k(const float* __restrict__ s0, bf16* __restrict__ d0,
                             const float* __restrict__ s1, bf16* __restrict__ d1,
                             const float* __restrict__ s2, bf16* __restrict__ d2, int n) {
    const int stride = gridDim.x * blockDim.x * 4;
    for (int i = (blockIdx.x * blockDim.x + threadIdx.x) * 4; i < n; i += stride) {
        float4 v0 = *(const float4*)(s0 + i);
        float4 v1 = *(const float4*)(s1 + i);
        float4 v2 = *(const float4*)(s2 + i);
        bf16x4 o0 = {(bf16)v0.x, (bf16)v0.y, (bf16)v0.z, (bf16)v0.w};
        bf16x4 o1 = {(bf16)v1.x, (bf16)v1.y, (bf16)v1.z, (bf16)v1.w};
        bf16x4 o2 = {(bf16)v2.x, (bf16)v2.y, (bf16)v2.z, (bf16)v2.w};
        *(bf16x4*)(d0 + i) = o0;
        *(bf16x4*)(d1 + i) = o1;
        *(bf16x4*)(d2 + i) = o2;
    }
}

// w2 [H][64][M] f32  ->  w2t [H][M][64] bf16
__global__ __launch_bounds__(256) void w2_transpose_k(const float* __restrict__ w2,
                                                      bf16* __restrict__ w2t, int M) {
    __shared__ float Tf[64][65];
    const int h = blockIdx.y, m0 = blockIdx.x * 64, t = threadIdx.x;
    {
        const int dr = t >> 4, c4 = (t & 15) * 4;
        #pragma unroll
        for (int it = 0; it < 4; ++it) {
            const int d = dr + it * 16;
            float4 v = *(const float4*)(w2 + ((size_t)h * 64 + d) * M + m0 + c4);
            Tf[d][c4] = v.x; Tf[d][c4 + 1] = v.y; Tf[d][c4 + 2] = v.z; Tf[d][c4 + 3] = v.w;
        }
    }
    __syncthreads();
    const int m = t >> 2;
    #pragma unroll
    for (int it = 0; it < 2; ++it) {
        const int ch = (t & 3) + it * 4;
        bf16x8 o;
        #pragma unroll
        for (int j = 0; j < 8; ++j) o[j] = (bf16)Tf[ch * 8 + j][m];
        *(bf16x8*)(w2t + ((size_t)h * M + m0 + m) * 64 + ch * 8) = o;
    }
}

// 128x128x64 bf16 MFMA GEMM (unchanged from R9: counted-vmcnt double buffer).
__global__ __launch_bounds__(256, 2) void gemm_bf16_k(const bf16* __restrict__ A,
                                                   const bf16* __restrict__ Bw,
                                                   const float* __restrict__ bias,
                                                   const float* __restrict__ bias2,
                                                   float* __restrict__ C0,
                                                   bf16* __restrict__ CK,
                                                   bf16* __restrict__ CV,
                                                   int M, int N, int K, int mode, int Ns)
{
    __shared__ __align__(16) bf16 As[2][128 * 64];
    __shared__ __align__(16) bf16 Bs[2][128 * 64];
    const int tid = threadIdx.x;
    const int w = tid >> 6, l = tid & 63;
    const int wr = w >> 1, wc = w & 1;
    const int lc = l & 15, lg = l >> 4;
    const int row0 = blockIdx.y * 128, col0 = blockIdx.x * 128;

    f32x4 acc[4][4] = {};

    const int nk = K >> 6;
    auto issue = [&](int buf, int k0) {
        #pragma unroll
        for (int i = 0; i < 4; ++i) {
            const int br = (w * 4 + i) * 8;
            const int r = br + (l >> 3);
            const int gs = (l & 7) ^ (r & 7);
            gld16(&As[buf][br * 64], A  + (size_t)(row0 + r) * K + k0 + gs * 8);
            gld16(&Bs[buf][br * 64], Bw + (size_t)(col0 + r) * K + k0 + gs * 8);
        }
    };

    issue(0, 0);
    int cur = 0;
    for (int kt = 0; kt < nk; ++kt) {
        if (kt + 1 < nk) {
            issue(cur ^ 1, (kt + 1) << 6);
            asm volatile("s_waitcnt vmcnt(8)" ::: "memory");
        } else {
            asm volatile("s_waitcnt vmcnt(0)" ::: "memory");
        }
        __builtin_amdgcn_s_barrier();
        #pragma unroll
        for (int ks = 0; ks < 2; ++ks) {
            bf16x8 af[4], bfv[4];
            #pragma unroll
            for (int i = 0; i < 4; ++i) {
                af[i]  = *(const bf16x8*)&As[cur][swz(wr * 64 + i * 16 + lc, ks * 4 + lg)];
                bfv[i] = *(const bf16x8*)&Bs[cur][swz(wc * 64 + i * 16 + lc, ks * 4 + lg)];
            }
            #pragma unroll
            for (int mi = 0; mi < 4; ++mi)
                #pragma unroll
                for (int ni = 0; ni < 4; ++ni)
                    acc[mi][ni] = __builtin_amdgcn_mfma_f32_16x16x32_bf16(af[mi], bfv[ni], acc[mi][ni], 0, 0, 0);
        }
        asm volatile("s_waitcnt lgkmcnt(0)" ::: "memory");
        __builtin_amdgcn_s_barrier();
        cur ^= 1;
    }

    #pragma unroll
    for (int ni = 0; ni < 4; ++ni) {
        const int col = col0 + wc * 64 + ni * 16 + lc;
        #pragma unroll
        for (int mi = 0; mi < 4; ++mi) {
            const int rowb = row0 + wr * 64 + mi * 16 + lg * 4;
            f32x4 v = acc[mi][ni];
            if (mode == 0) {
                const float bv = bias[col];
                #pragma unroll
                for (int r = 0; r < 4; ++r)
                    C0[(size_t)(rowb + r) * N + col] = v[r] + bv;
            } else if (col < Ns) {
                const float bv = bias[col];
                #pragma unroll
                for (int r = 0; r < 4; ++r)
                    CK[(size_t)(rowb + r) * Ns + col] = (bf16)fmaxf(v[r] + bv, 0.f);
            } else {
                const float bv = bias2[col - Ns];
                const int b = rowb >> 11, tt = rowb & 2047;   // T = 2048
                bf16x4 o = {(bf16)(v[0] + bv), (bf16)(v[1] + bv),
                            (bf16)(v[2] + bv), (bf16)(v[3] + bv)};
                *(bf16x4*)(CV + ((size_t)b * Ns + (col - Ns)) * 2048 + tt) = o;
            }
        }
    }
}

// v10: 32x32x16 MFMA attention, 32 q-rows per wave, P fully in registers.
// Swapped QK: S^T[s][q] = mfma(A=W s-rows, B=K q-cols) -> lane holds P column
// q=lane&31 (= PV A-frag row requirement). pa fragments assembled via
// shfl_xor(32) + hi-select. 4-wave blocks own q-tiles {a, 31-a}; 3-buffer W/V
// ring with counted vmcnt(4); b2 in LDS. No P LDS, no per-iter LDS writes.
__global__ __launch_bounds__(256, 2) void synth_attn_v10(const bf16* __restrict__ Kb,
                                                         const bf16* __restrict__ VT,
                                                         const bf16* __restrict__ w2t,
                                                         const float* __restrict__ b2,
                                                         bf16* __restrict__ Ob)
{
    constexpr int T = 2048, C = 1024, M = 2048;
    __shared__ __align__(16) bf16 Wl[3][64 * 64];   // [s][d], src-XOR swizzled
    __shared__ __align__(16) bf16 Vl[3][64 * 64];   // [d][s], src-XOR swizzled
    __shared__ float b2l[M];
    const int tid = threadIdx.x;
    const int w = tid >> 6, l = tid & 63;
    const int c = l & 31, hi = l >> 5;

    // block -> (b, h, a); blocks bx and bx+256 carry a and 15-a so each CU
    // totals 49 iterations under round-robin dispatch.
    const int bx = blockIdx.x;
    const int hseg = bx >> 8, idx = bx & 255;
    const int jj = idx & 15;
    const int a = hseg ? (15 - jj) : jj;
    const int bh = (hseg << 4) | (idx >> 4);
    const int h = bh & 15, b = bh >> 4;
    const int tA = a, tB = 31 - a;
    const int myT = (w >> 1) ? tA : tB;       // waves 0,1 -> tB; 2,3 -> tA
    const int t0w = myT * 64 + (w & 1) * 32;  // wave's 32 q-rows

    // b2 -> LDS (256 threads x 8 floats)
    *(float4*)&b2l[tid * 8]     = *(const float4*)(b2 + tid * 8);
    *(float4*)&b2l[tid * 8 + 4] = *(const float4*)(b2 + tid * 8 + 4);
    __syncthreads();

    const bf16* Wgt = w2t + (size_t)h * M * 64;            // [s][64] rows
    const bf16* Vgt = VT + ((size_t)b * C + h * 64) * T;   // [d][T] rows

    // K fragments: B[k=d][col=q]: lane owns q = c; 4 k-slots of 16 d
    const bf16* Kg = Kb + (size_t)(b * T + t0w + c) * C + h * 64 + hi * 8;
    bf16x8 kf[4];
    #pragma unroll
    for (int kst = 0; kst < 4; ++kst) kf[kst] = *(const bf16x8*)(Kg + kst * 16);

    // prologue: stage s-tiles 0 and 1 (tB >= 16, both exist)
    stage16(&Wl[0][0], Wgt, 64, w, l);
    stage16(&Vl[0][0], Vgt, T, w, l);
    stage16(&Wl[1][0], Wgt + (size_t)64 * 64, 64, w, l);
    stage16(&Vl[1][0], Vgt + 64, T, w, l);

    f32x16 o0 = {}, o1 = {};
    float lsum = 0.f;

    int cur = 0;
    for (int sb = 0; sb <= tB; ++sb) {
        const int s0 = sb * 64;
        // my 4 loads for tile sb done; tile sb+1's 4 may stay in flight
        if (sb < tB) asm volatile("s_waitcnt vmcnt(4)" ::: "memory");
        else         asm volatile("s_waitcnt vmcnt(0)" ::: "memory");
        __builtin_amdgcn_s_barrier();

        if (sb <= myT) {
            const bf16* Wb = &Wl[cur][0];
            const bf16* Vb = &Vl[cur][0];

            // S^T = W.K + b2: C-init from b2l (row s per reg quad)
            f32x16 sv0, sv1;
            #pragma unroll
            for (int qd = 0; qd < 4; ++qd) {
                float4 b4 = *(const float4*)&b2l[s0 + qd * 8 + 4 * hi];
                float4 b5 = *(const float4*)&b2l[s0 + 32 + qd * 8 + 4 * hi];
                sv0[4*qd] = b4.x; sv0[4*qd+1] = b4.y; sv0[4*qd+2] = b4.z; sv0[4*qd+3] = b4.w;
                sv1[4*qd] = b5.x; sv1[4*qd+1] = b5.y; sv1[4*qd+2] = b5.z; sv1[4*qd+3] = b5.w;
            }
            #pragma unroll
            for (int kst = 0; kst < 4; ++kst) {
                bf16x8 w0 = *(const bf16x8*)&Wb[swz(c,      kst * 2 + hi)];
                bf16x8 w1 = *(const bf16x8*)&Wb[swz(32 + c, kst * 2 + hi)];
                sv0 = __builtin_amdgcn_mfma_f32_32x32x16_bf16(w0, kf[kst], sv0, 0, 0, 0);
                sv1 = __builtin_amdgcn_mfma_f32_32x32x16_bf16(w1, kf[kst], sv1, 0, 0, 0);
            }

            // exp (exact no-max), causal mask on diag, pack to bf16 u32 pairs
            const bool diag = (sb == myT);
            const int qv = (w & 1) * 32 + c;
            u32 U0[8], U1[8];
            #pragma unroll
            for (int qd = 0; qd < 4; ++qd) {
                float e0[4], e1[4];
                #pragma unroll
                for (int k = 0; k < 4; ++k) {
                    const int sbase = qd * 8 + 4 * hi + k;   // tile-local s
                    float ev0 = __expf(sv0[4*qd + k]);
                    float ev1 = __expf(sv1[4*qd + k]);
                    if (diag && sbase > qv)      ev0 = 0.f;
                    if (diag && sbase + 32 > qv) ev1 = 0.f;
                    lsum += ev0 + ev1;
                    e0[k] = ev0; e1[k] = ev1;
                }
                union { bf16x4 v; u32 u[2]; } p0, p1;
                p0.v = {(bf16)e0[0], (bf16)e0[1], (bf16)e0[2], (bf16)e0[3]};
                p1.v = {(bf16)e1[0], (bf16)e1[1], (bf16)e1[2], (bf16)e1[3]};
                U0[2*qd] = p0.u[0]; U0[2*qd+1] = p0.u[1];
                U1[2*qd] = p1.u[0]; U1[2*qd+1] = p1.u[1];
            }

            // PV: assemble pa fragments in-register, O += P.V
            #define PV_TILE(Uarr, st)                                              \
            {                                                                      \
                _Pragma("unroll")                                                  \
                for (int kk = 0; kk < 2; ++kk) {                                   \
                    u32 A00 = Uarr[4*kk],   A01 = Uarr[4*kk+1];                    \
                    u32 A10 = Uarr[4*kk+2], A11 = Uarr[4*kk+3];                    \
                    u32 s00 = (u32)__shfl_xor((int)A00, 32);                       \
                    u32 s01 = (u32)__shfl_xor((int)A01, 32);                       \
                    u32 s10 = (u32)__shfl_xor((int)A10, 32);                       \
                    u32 s11 = (u32)__shfl_xor((int)A11, 32);                       \
                    union { u32 u[4]; bf16x8 v; } pa;                              \
                    pa.u[0] = hi ? s10 : A00;                                      \
                    pa.u[1] = hi ? s11 : A01;                                      \
                    pa.u[2] = hi ? A10 : s00;                                      \
                    pa.u[3] = hi ? A11 : s01;                                      \
                    const int ch = (st) * 4 + kk * 2 + hi;                         \
                    bf16x8 v0 = *(const bf16x8*)&Vb[swz(c,      ch)];              \
                    bf16x8 v1 = *(const bf16x8*)&Vb[swz(32 + c, ch)];              \
                    o0 = __builtin_amdgcn_mfma_f32_32x32x16_bf16(pa.v, v0, o0, 0, 0, 0); \
                    o1 = __builtin_amdgcn_mfma_f32_32x32x16_bf16(pa.v, v1, o1, 0, 0, 0); \
                }                                                                  \
            }
            PV_TILE(U0, 0)
            PV_TILE(U1, 1)
            #undef PV_TILE
        }

        // stage tile sb+2 into buf (sb+2)%3: its readers crossed this barrier
        if (sb + 2 <= tB) {
            int nx = cur + 2; if (nx >= 3) nx -= 3;
            stage16(&Wl[nx][0], Wgt + (size_t)(s0 + 128) * 64, 64, w, l);
            stage16(&Vl[nx][0], Vgt + (s0 + 128), T, w, l);
        }
        if (++cur == 3) cur = 0;
    }

    // epilogue: full row-sum per q=c (own half + partner half), then per-reg
    // redistribute the inverse via shfl from lane q'.
    const float inv = 1.f / (lsum + __shfl_xor(lsum, 32));
    #pragma unroll
    for (int r = 0; r < 16; ++r) {
        const int q_ = (r & 3) + 8 * (r >> 2) + 4 * hi;
        const float iv = __shfl(inv, q_);
        bf16* dst = Ob + (size_t)(b * T + t0w + q_) * C + h * 64;
        dst[c]      = (bf16)(o0[r] * iv);
        dst[32 + c] = (bf16)(o1[r] * iv);
    }
}

extern "C" void kernel_launch(void* const* d_in, const int* in_sizes, int n_in,
                              void* d_out, int out_size, void* d_ws, size_t ws_size,
                              hipStream_t stream) {
    const float* x       = (const float*)d_in[0];
    const float* w1_w    = (const float*)d_in[1];
    const float* w1_b    = (const float*)d_in[2];
    const float* w2      = (const float*)d_in[3];
    const float* b2      = (const float*)d_in[4];
    const float* value_w = (const float*)d_in[5];
    const float* value_b = (const float*)d_in[6];
    const float* proj_w  = (const float*)d_in[7];
    const float* proj_b  = (const float*)d_in[8];

    const int B = 2, T = 2048, C = 1024, H = 16, M = 2048;
    const int R = B * T;   // 4096

    bf16* xb  = (bf16*)d_ws;                  // [R][C]
    bf16* w1b = xb  + (size_t)R * C;          // [C][C]   } contiguous ->
    bf16* vwb = w1b + (size_t)C * C;          // [C][C]   } fused B [2C][C]
    bf16* w2t = vwb + (size_t)C * C;          // [H][M][64]
    bf16* pwb = w2t + (size_t)H * M * 64;     // [C][C]
    bf16* Kb  = pwb + (size_t)C * C;          // [R][C]
    bf16* VTb = Kb  + (size_t)R * C;          // [B][C][T]
    bf16* Ob  = VTb + (size_t)R * C;          // [R][C]    total 42 MB

    cast_bf16_k<<<1024, 256, 0, stream>>>(x, xb, R * C);
    cast3_bf16_k<<<512, 256, 0, stream>>>(w1_w, w1b, value_w, vwb, proj_w, pwb, C * C);
    w2_transpose_k<<<dim3(M / 64, H), 256, 0, stream>>>(w2, w2t, M);

    // fused K/V GEMM: N = 2C, B-operand = [w1b ; vwb]
    gemm_bf16_k<<<dim3(2 * C / 128, R / 128), 256, 0, stream>>>(
        xb, w1b, w1_b, value_b, nullptr, Kb, VTb, R, 2 * C, C, 1, C);

    synth_attn_v10<<<dim3(512), 256, 0, stream>>>(Kb, VTb, w2t, b2, Ob);

    gemm_bf16_k<<<dim3(C / 128, R / 128), 256, 0, stream>>>(
        Ob, pwb, proj_b, nullptr, (float*)d_out, nullptr, nullptr, R, C, C, 0, C);
}

// Round 11
// 109.925 us; speedup vs baseline: 1.0343x; 1.0343x over previous
//
#include <hip/hip_runtime.h>
#include <math.h>
#include <stdint.h>

typedef __bf16 bf16;
typedef __bf16 bf16x8 __attribute__((ext_vector_type(8)));
typedef __bf16 bf16x4 __attribute__((ext_vector_type(4)));
typedef float f32x4 __attribute__((ext_vector_type(4)));
typedef float f32x16 __attribute__((ext_vector_type(16)));
typedef unsigned int u32;

// element index into a [rows][64] bf16 tile, XOR-swizzled in 16B (8-elem) chunks
__device__ __forceinline__ int swz(int row, int chunk) {
    return row * 64 + ((chunk ^ (row & 7)) << 3);
}

// async 16B global->LDS; lds must be wave-uniform base (HW adds lane*16)
__device__ __forceinline__ void gld16(void* lds, const void* g) {
    __builtin_amdgcn_global_load_lds(
        (const __attribute__((address_space(1))) u32*)g,
        (__attribute__((address_space(3))) u32*)lds, 16, 0, 0);
}

__global__ void cast_bf16_k(const float* __restrict__ src, bf16* __restrict__ dst, int n) {
    const int stride = gridDim.x * blockDim.x * 4;
    for (int i = (blockIdx.x * blockDim.x + threadIdx.x) * 4; i < n; i += stride) {
        float4 v = *(const float4*)(src + i);
        bf16x4 o = {(bf16)v.x, (bf16)v.y, (bf16)v.z, (bf16)v.w};
        *(bf16x4*)(dst + i) = o;
    }
}

__global__ void cast3_bf16_k(const float* __restrict__ s0, bf16* __restrict__ d0,
                             const float* __restrict__ s1, bf16* __restrict__ d1,
                             const float* __restrict__ s2, bf16* __restrict__ d2, int n) {
    const int stride = gridDim.x * blockDim.x * 4;
    for (int i = (blockIdx.x * blockDim.x + threadIdx.x) * 4; i < n; i += stride) {
        float4 v0 = *(const float4*)(s0 + i);
        float4 v1 = *(const float4*)(s1 + i);
        float4 v2 = *(const float4*)(s2 + i);
        bf16x4 o0 = {(bf16)v0.x, (bf16)v0.y, (bf16)v0.z, (bf16)v0.w};
        bf16x4 o1 = {(bf16)v1.x, (bf16)v1.y, (bf16)v1.z, (bf16)v1.w};
        bf16x4 o2 = {(bf16)v2.x, (bf16)v2.y, (bf16)v2.z, (bf16)v2.w};
        *(bf16x4*)(d0 + i) = o0;
        *(bf16x4*)(d1 + i) = o1;
        *(bf16x4*)(d2 + i) = o2;
    }
}

// w2 [H][64][M] f32  ->  w2t [H][M][64] bf16
__global__ __launch_bounds__(256) void w2_transpose_k(const float* __restrict__ w2,
                                                      bf16* __restrict__ w2t, int M) {
    __shared__ float Tf[64][65];
    const int h = blockIdx.y, m0 = blockIdx.x * 64, t = threadIdx.x;
    {
        const int dr = t >> 4, c4 = (t & 15) * 4;
        #pragma unroll
        for (int it = 0; it < 4; ++it) {
            const int d = dr + it * 16;
            float4 v = *(const float4*)(w2 + ((size_t)h * 64 + d) * M + m0 + c4);
            Tf[d][c4] = v.x; Tf[d][c4 + 1] = v.y; Tf[d][c4 + 2] = v.z; Tf[d][c4 + 3] = v.w;
        }
    }
    __syncthreads();
    const int m = t >> 2;
    #pragma unroll
    for (int it = 0; it < 2; ++it) {
        const int ch = (t & 3) + it * 4;
        bf16x8 o;
        #pragma unroll
        for (int j = 0; j < 8; ++j) o[j] = (bf16)Tf[ch * 8 + j][m];
        *(bf16x8*)(w2t + ((size_t)h * M + m0 + m) * 64 + ch * 8) = o;
    }
}

// 128x128x64 bf16 MFMA GEMM (R9-verified: counted-vmcnt double buffer).
__global__ __launch_bounds__(256, 2) void gemm_bf16_k(const bf16* __restrict__ A,
                                                   const bf16* __restrict__ Bw,
                                                   const float* __restrict__ bias,
                                                   const float* __restrict__ bias2,
                                                   float* __restrict__ C0,
                                                   bf16* __restrict__ CK,
                                                   bf16* __restrict__ CV,
                                                   int M, int N, int K, int mode, int Ns)
{
    __shared__ __align__(16) bf16 As[2][128 * 64];
    __shared__ __align__(16) bf16 Bs[2][128 * 64];
    const int tid = threadIdx.x;
    const int w = tid >> 6, l = tid & 63;
    const int wr = w >> 1, wc = w & 1;
    const int lc = l & 15, lg = l >> 4;
    const int row0 = blockIdx.y * 128, col0 = blockIdx.x * 128;

    f32x4 acc[4][4] = {};

    const int nk = K >> 6;
    auto issue = [&](int buf, int k0) {
        #pragma unroll
        for (int i = 0; i < 4; ++i) {
            const int br = (w * 4 + i) * 8;
            const int r = br + (l >> 3);
            const int gs = (l & 7) ^ (r & 7);
            gld16(&As[buf][br * 64], A  + (size_t)(row0 + r) * K + k0 + gs * 8);
            gld16(&Bs[buf][br * 64], Bw + (size_t)(col0 + r) * K + k0 + gs * 8);
        }
    };

    issue(0, 0);
    int cur = 0;
    for (int kt = 0; kt < nk; ++kt) {
        if (kt + 1 < nk) {
            issue(cur ^ 1, (kt + 1) << 6);
            asm volatile("s_waitcnt vmcnt(8)" ::: "memory");
        } else {
            asm volatile("s_waitcnt vmcnt(0)" ::: "memory");
        }
        __builtin_amdgcn_s_barrier();
        #pragma unroll
        for (int ks = 0; ks < 2; ++ks) {
            bf16x8 af[4], bfv[4];
            #pragma unroll
            for (int i = 0; i < 4; ++i) {
                af[i]  = *(const bf16x8*)&As[cur][swz(wr * 64 + i * 16 + lc, ks * 4 + lg)];
                bfv[i] = *(const bf16x8*)&Bs[cur][swz(wc * 64 + i * 16 + lc, ks * 4 + lg)];
            }
            #pragma unroll
            for (int mi = 0; mi < 4; ++mi)
                #pragma unroll
                for (int ni = 0; ni < 4; ++ni)
                    acc[mi][ni] = __builtin_amdgcn_mfma_f32_16x16x32_bf16(af[mi], bfv[ni], acc[mi][ni], 0, 0, 0);
        }
        asm volatile("s_waitcnt lgkmcnt(0)" ::: "memory");
        __builtin_amdgcn_s_barrier();
        cur ^= 1;
    }

    #pragma unroll
    for (int ni = 0; ni < 4; ++ni) {
        const int col = col0 + wc * 64 + ni * 16 + lc;
        #pragma unroll
        for (int mi = 0; mi < 4; ++mi) {
            const int rowb = row0 + wr * 64 + mi * 16 + lg * 4;
            f32x4 v = acc[mi][ni];
            if (mode == 0) {
                const float bv = bias[col];
                #pragma unroll
                for (int r = 0; r < 4; ++r)
                    C0[(size_t)(rowb + r) * N + col] = v[r] + bv;
            } else if (col < Ns) {
                const float bv = bias[col];
                #pragma unroll
                for (int r = 0; r < 4; ++r)
                    CK[(size_t)(rowb + r) * Ns + col] = (bf16)fmaxf(v[r] + bv, 0.f);
            } else {
                const float bv = bias2[col - Ns];
                const int b = rowb >> 11, tt = rowb & 2047;   // T = 2048
                bf16x4 o = {(bf16)(v[0] + bv), (bf16)(v[1] + bv),
                            (bf16)(v[2] + bv), (bf16)(v[3] + bv)};
                *(bf16x4*)(CV + ((size_t)b * Ns + (col - Ns)) * 2048 + tt) = o;
            }
        }
    }
}

// v11: 128-row q-tiles, 8 waves = 2 s-parity groups x 4 q-subtiles (32q each,
// 32x32x16 MFMA, v10-verified fragment math). W/V tiles staged in
// FRAGMENT-PACKED LINEAR LDS layout (slot*1KB + lane*16B) -> all ds_read_b128
// conflict-free; per-group 2-buffer ring with counted vmcnt(4). Exact no-max
// softmax lets s-tiles split across groups with partial-sum merge at epilogue.
__global__ __launch_bounds__(512, 4) void synth_attn_v11(const bf16* __restrict__ Kb,
                                                         const bf16* __restrict__ VT,
                                                         const bf16* __restrict__ w2t,
                                                         const float* __restrict__ b2,
                                                         bf16* __restrict__ Ob)
{
    constexpr int T = 2048, C = 1024, M = 2048;
    // ring[sg][buf]: W tile at [0..4096), V tile at [4096..8192) (bf16 elems)
    __shared__ __align__(16) bf16 ring[2][2][8192];   // 64 KB
    __shared__ float b2l[M];                          // 8 KB
    const int tid = threadIdx.x;
    const int w = tid >> 6, l = tid & 63;
    const int c = l & 31, hi = l >> 5;
    const int sg = w & 1, qh = w >> 1;                // s-parity group, q-subtile

    // block -> (b, h, t128); CU u gets rounds {v, 15-v} -> uniform wall time
    const int bx = blockIdx.x;
    const int u = bx & 255, rg = bx >> 8;             // grid = 512
    const int t128 = rg ? (15 - (u & 15)) : (u & 15);
    const int bh = (u >> 4) + (rg << 4);
    const int h = bh & 15, b = bh >> 4;
    const int t0w = t128 * 128 + qh * 32;             // wave's 32 q-rows
    const int myT = 2 * t128 + (qh >> 1);             // last s-tile for this wave

    // b2 -> LDS (512 threads x 4 floats)
    *(float4*)&b2l[tid * 4] = *(const float4*)(b2 + tid * 4);
    __syncthreads();

    const bf16* Wg = w2t + (size_t)h * M * 64;            // [s][64] rows
    const bf16* Vg = VT + ((size_t)b * C + h * 64) * T;   // [d][T] rows

    // K fragments (B-operand of swapped QK): lane owns q=c, 4 k-slots of 16 d
    const bf16* Kg = Kb + ((size_t)(b * T + t0w + c)) * C + h * 64 + hi * 8;
    bf16x8 kf[4];
    #pragma unroll
    for (int kst = 0; kst < 4; ++kst) kf[kst] = *(const bf16x8*)(Kg + kst * 16);

    // stage this group's tile for s-tile sb into ring[sg][buf]; 4 gld16/wave.
    // LDS layout: W slot j = r*4+kst holds lane-16B = W[s0+r*32+(l&31)][kst*16+(l>>5)*8]
    //             V slot j = r*4+m   holds lane-16B = V[d=r*32+(l&31)][s0+m*16+(l>>5)*8]
    auto stage = [&](int buf, int sb) {
        bf16* dst = &ring[sg][buf][0];
        const int s0 = sb * 64;
        const int jb = (qh & 1) * 4;                  // slots 0-3 or 4-7
        if (qh < 2) {                                 // W slots
            #pragma unroll
            for (int j = 0; j < 4; ++j) {
                const int jj = jb + j, r = jj >> 2, kst = jj & 3;
                gld16(dst + jj * 512,
                      Wg + ((size_t)(s0 + r * 32 + c)) * 64 + kst * 16 + hi * 8);
            }
        } else {                                      // V slots
            #pragma unroll
            for (int j = 0; j < 4; ++j) {
                const int jj = jb + j, r = jj >> 2, m = jj & 3;
                gld16(dst + 4096 + jj * 512,
                      Vg + ((size_t)(r * 32 + c)) * T + s0 + m * 16 + hi * 8);
            }
        }
    };

    const int nIter = t128 + 1;
    stage(0, sg);                                     // prologue: s-tile sg

    f32x16 o0 = {}, o1 = {};
    float lsum = 0.f;

    for (int i = 0; i < nIter; ++i) {
        const int sb = 2 * i + sg;
        if (i + 1 < nIter) {
            stage((i + 1) & 1, sb + 2);
            asm volatile("s_waitcnt vmcnt(4)" ::: "memory");   // tile i ready
        } else {
            asm volatile("s_waitcnt vmcnt(0)" ::: "memory");
        }
        __builtin_amdgcn_s_barrier();

        if (sb <= myT) {
            const bf16* Wb = &ring[sg][i & 1][0];
            const bf16* Vb = &ring[sg][i & 1][4096];
            const int s0 = sb * 64;

            // S^T = W.K + b2 (C-init from b2l; rows = s)
            f32x16 sv0, sv1;
            #pragma unroll
            for (int qd = 0; qd < 4; ++qd) {
                float4 b4 = *(const float4*)&b2l[s0 + qd * 8 + 4 * hi];
                float4 b5 = *(const float4*)&b2l[s0 + 32 + qd * 8 + 4 * hi];
                sv0[4*qd] = b4.x; sv0[4*qd+1] = b4.y; sv0[4*qd+2] = b4.z; sv0[4*qd+3] = b4.w;
                sv1[4*qd] = b5.x; sv1[4*qd+1] = b5.y; sv1[4*qd+2] = b5.z; sv1[4*qd+3] = b5.w;
            }
            #pragma unroll
            for (int kst = 0; kst < 4; ++kst) {
                bf16x8 w0 = *(const bf16x8*)&Wb[kst * 512 + l * 8];
                bf16x8 w1 = *(const bf16x8*)&Wb[(4 + kst) * 512 + l * 8];
                sv0 = __builtin_amdgcn_mfma_f32_32x32x16_bf16(w0, kf[kst], sv0, 0, 0, 0);
                sv1 = __builtin_amdgcn_mfma_f32_32x32x16_bf16(w1, kf[kst], sv1, 0, 0, 0);
            }

            // exp (exact no-max), causal mask on diag tile, pack to bf16 pairs
            const bool diag = (sb == myT);
            const int qv = (qh & 1) * 32 + c;         // q-pos within the 64-s diag tile
            u32 U0[8], U1[8];
            #pragma unroll
            for (int qd = 0; qd < 4; ++qd) {
                float e0[4], e1[4];
                #pragma unroll
                for (int k = 0; k < 4; ++k) {
                    const int sbase = qd * 8 + 4 * hi + k;
                    float ev0 = __expf(sv0[4*qd + k]);
                    float ev1 = __expf(sv1[4*qd + k]);
                    if (diag && sbase > qv)      ev0 = 0.f;
                    if (diag && sbase + 32 > qv) ev1 = 0.f;
                    lsum += ev0 + ev1;
                    e0[k] = ev0; e1[k] = ev1;
                }
                union { bf16x4 v; u32 uu[2]; } p0, p1;
                p0.v = {(bf16)e0[0], (bf16)e0[1], (bf16)e0[2], (bf16)e0[3]};
                p1.v = {(bf16)e1[0], (bf16)e1[1], (bf16)e1[2], (bf16)e1[3]};
                U0[2*qd] = p0.uu[0]; U0[2*qd+1] = p0.uu[1];
                U1[2*qd] = p1.uu[0]; U1[2*qd+1] = p1.uu[1];
            }

            // PV: assemble pa fragments in-register, O += P.V (v10-verified)
            #define PV_TILE(Uarr, st)                                              \
            {                                                                      \
                _Pragma("unroll")                                                  \
                for (int kk = 0; kk < 2; ++kk) {                                   \
                    u32 A00 = Uarr[4*kk],   A01 = Uarr[4*kk+1];                    \
                    u32 A10 = Uarr[4*kk+2], A11 = Uarr[4*kk+3];                    \
                    u32 s00 = (u32)__shfl_xor((int)A00, 32);                       \
                    u32 s01 = (u32)__shfl_xor((int)A01, 32);                       \
                    u32 s10 = (u32)__shfl_xor((int)A10, 32);                       \
                    u32 s11 = (u32)__shfl_xor((int)A11, 32);                       \
                    union { u32 uu[4]; bf16x8 v; } pa;                             \
                    pa.uu[0] = hi ? s10 : A00;                                     \
                    pa.uu[1] = hi ? s11 : A01;                                     \
                    pa.uu[2] = hi ? A10 : s00;                                     \
                    pa.uu[3] = hi ? A11 : s01;                                     \
                    const int m = (st) * 2 + kk;                                   \
                    bf16x8 v0 = *(const bf16x8*)&Vb[m * 512 + l * 8];              \
                    bf16x8 v1 = *(const bf16x8*)&Vb[(4 + m) * 512 + l * 8];        \
                    o0 = __builtin_amdgcn_mfma_f32_32x32x16_bf16(pa.v, v0, o0, 0, 0, 0); \
                    o1 = __builtin_amdgcn_mfma_f32_32x32x16_bf16(pa.v, v1, o1, 0, 0, 0); \
                }                                                                  \
            }
            PV_TILE(U0, 0)
            PV_TILE(U1, 1)
            #undef PV_TILE
        }

        asm volatile("s_waitcnt lgkmcnt(0)" ::: "memory");
        __builtin_amdgcn_s_barrier();
    }

    // epilogue: merge the two s-group partials per q-subtile via LDS scratch
    // (ring memory is free: all loads drained, all reads barriered).
    float* scr = (float*)&ring[0][0][0];
    float* base = scr + qh * 2112;   // 33*64 floats per q-subtile slot
    if (sg == 1) {
        #pragma unroll
        for (int k = 0; k < 16; ++k) base[k * 64 + l] = o0[k];
        #pragma unroll
        for (int k = 0; k < 16; ++k) base[(16 + k) * 64 + l] = o1[k];
        base[32 * 64 + l] = lsum;
    }
    __syncthreads();
    if (sg == 0) {
        #pragma unroll
        for (int k = 0; k < 16; ++k) o0[k] += base[k * 64 + l];
        #pragma unroll
        for (int k = 0; k < 16; ++k) o1[k] += base[(16 + k) * 64 + l];
        lsum += base[32 * 64 + l];
        const float inv = 1.f / (lsum + __shfl_xor(lsum, 32));
        #pragma unroll
        for (int r = 0; r < 16; ++r) {
            const int q_ = (r & 3) + 8 * (r >> 2) + 4 * hi;
            const float iv = __shfl(inv, q_);
            bf16* dst = Ob + (size_t)(b * T + t0w + q_) * C + h * 64;
            dst[c]      = (bf16)(o0[r] * iv);
            dst[32 + c] = (bf16)(o1[r] * iv);
        }
    }
}

extern "C" void kernel_launch(void* const* d_in, const int* in_sizes, int n_in,
                              void* d_out, int out_size, void* d_ws, size_t ws_size,
                              hipStream_t stream) {
    const float* x       = (const float*)d_in[0];
    const float* w1_w    = (const float*)d_in[1];
    const float* w1_b    = (const float*)d_in[2];
    const float* w2      = (const float*)d_in[3];
    const float* b2      = (const float*)d_in[4];
    const float* value_w = (const float*)d_in[5];
    const float* value_b = (const float*)d_in[6];
    const float* proj_w  = (const float*)d_in[7];
    const float* proj_b  = (const float*)d_in[8];

    const int B = 2, T = 2048, C = 1024, H = 16, M = 2048;
    const int R = B * T;   // 4096

    bf16* xb  = (bf16*)d_ws;                  // [R][C]
    bf16* w1b = xb  + (size_t)R * C;          // [C][C]   } contiguous ->
    bf16* vwb = w1b + (size_t)C * C;          // [C][C]   } fused B [2C][C]
    bf16* w2t = vwb + (size_t)C * C;          // [H][M][64]
    bf16* pwb = w2t + (size_t)H * M * 64;     // [C][C]
    bf16* Kb  = pwb + (size_t)C * C;          // [R][C]
    bf16* VTb = Kb  + (size_t)R * C;          // [B][C][T]
    bf16* Ob  = VTb + (size_t)R * C;          // [R][C]    total 42 MB

    cast_bf16_k<<<1024, 256, 0, stream>>>(x, xb, R * C);
    cast3_bf16_k<<<512, 256, 0, stream>>>(w1_w, w1b, value_w, vwb, proj_w, pwb, C * C);
    w2_transpose_k<<<dim3(M / 64, H), 256, 0, stream>>>(w2, w2t, M);

    // fused K/V GEMM: N = 2C, B-operand = [w1b ; vwb]
    gemm_bf16_k<<<dim3(2 * C / 128, R / 128), 256, 0, stream>>>(
        xb, w1b, w1_b, value_b, nullptr, Kb, VTb, R, 2 * C, C, 1, C);

    synth_attn_v11<<<dim3(512), 512, 0, stream>>>(Kb, VTb, w2t, b2, Ob);

    gemm_bf16_k<<<dim3(C / 128, R / 128), 256, 0, stream>>>(
        Ob, pwb, proj_b, nullptr, (float*)d_out, nullptr, nullptr, R, C, C, 0, C);
}